// Round 13
// baseline (31.502 us; speedup 1.0000x reference)
//
#include <hip/hip_runtime.h>

typedef short bf16x8 __attribute__((ext_vector_type(8)));
typedef float f32x4  __attribute__((ext_vector_type(4)));

constexpr int C  = 640;
constexpr int HW = 25;
constexpr int PSTRIDE = 736;   // ws floats per gram block: 625 G + 100 moments + pad

__device__ __forceinline__ float rl(float x, int lane) {
  return __uint_as_float(__builtin_amdgcn_readlane(__float_as_uint(x), lane));
}

// pack 2 fp32 -> (hi-bf16 pair, lo-bf16 pair), truncating split
__device__ __forceinline__ void packpair(float x0, float x1, unsigned& h, unsigned& l) {
  unsigned u0 = __float_as_uint(x0), u1 = __float_as_uint(x1);
  h = __builtin_amdgcn_perm(u1, u0, 0x07060302u);      // [u1.hi16 : u0.hi16]
  float l0 = x0 - __uint_as_float(u0 & 0xFFFF0000u);
  float l1 = x1 - __uint_as_float(u1 & 0xFFFF0000u);
  l = __builtin_amdgcn_perm(__float_as_uint(l1), __float_as_uint(l0), 0x07060302u);
}

// ---------- Kernel 1: half-sample Gram via MFMA (320 channels), 5 waves ----------
__global__ __launch_bounds__(320) void emd_gram(
    const float* __restrict__ support, const float* __restrict__ query,
    float* __restrict__ part)
{
  const int bid = blockIdx.x, tid = threadIdx.x;
  const int n = bid >> 1, h = bid & 1;
  const int wid = tid >> 6, lane = tid & 63;
  const int lg = lane >> 4, lr = lane & 15;

  __shared__ float accbuf[5][64][16];   // 20 KB
  __shared__ float mombuf[5][8][64];    // 10 KB

  const float* Qg = query   + (size_t)n * C * HW;
  const float* Sg = support + (size_t)n * C * HW;

  f32x4 acc[2][2];
  {
    f32x4 z = {0.f, 0.f, 0.f, 0.f};
    acc[0][0] = z; acc[0][1] = z; acc[1][0] = z; acc[1][1] = z;
  }
  float mq[2] = {0.f, 0.f}, mq2[2] = {0.f, 0.f};
  float ms[2] = {0.f, 0.f}, ms2[2] = {0.f, 0.f};

  #pragma unroll 1
  for (int kc = 0; kc < 2; ++kc) {
    const int c0 = h * 320 + wid * 64 + kc * 32 + lg * 8;
    const float* qb = Qg + c0 * HW;
    const float* sb = Sg + c0 * HW;
    bf16x8 Ah[2], Al[2], Bh[2], Bl[2];
    #pragma unroll
    for (int t = 0; t < 2; ++t) {
      const int row = t * 16 + lr;
      const bool ok = row < 25;
      float xq[8], xs[8];
      #pragma unroll
      for (int j = 0; j < 8; ++j) {
        xq[j] = ok ? qb[j * HW + row] : 0.f;
        xs[j] = ok ? sb[j * HW + row] : 0.f;
      }
      #pragma unroll
      for (int j = 0; j < 8; ++j) {
        mq[t] += xq[j]; mq2[t] = fmaf(xq[j], xq[j], mq2[t]);
        ms[t] += xs[j]; ms2[t] = fmaf(xs[j], xs[j], ms2[t]);
      }
      union { unsigned u[4]; bf16x8 v; } ah, al, bh, bl;
      #pragma unroll
      for (int jj = 0; jj < 4; ++jj) {
        packpair(xq[2 * jj], xq[2 * jj + 1], ah.u[jj], al.u[jj]);
        packpair(xs[2 * jj], xs[2 * jj + 1], bh.u[jj], bl.u[jj]);
      }
      Ah[t] = ah.v; Al[t] = al.v; Bh[t] = bh.v; Bl[t] = bl.v;
    }
    #pragma unroll
    for (int tr = 0; tr < 2; ++tr)
      #pragma unroll
      for (int tc = 0; tc < 2; ++tc) {
        acc[tr][tc] = __builtin_amdgcn_mfma_f32_16x16x32_bf16(Ah[tr], Bh[tc], acc[tr][tc], 0, 0, 0);
        acc[tr][tc] = __builtin_amdgcn_mfma_f32_16x16x32_bf16(Ah[tr], Bl[tc], acc[tr][tc], 0, 0, 0);
        acc[tr][tc] = __builtin_amdgcn_mfma_f32_16x16x32_bf16(Al[tr], Bh[tc], acc[tr][tc], 0, 0, 0);
      }
  }

  #pragma unroll
  for (int tr = 0; tr < 2; ++tr)
    #pragma unroll
    for (int tc = 0; tc < 2; ++tc)
      *reinterpret_cast<f32x4*>(&accbuf[wid][lane][(tr * 2 + tc) * 4]) = acc[tr][tc];
  mombuf[wid][0][lane] = mq[0];  mombuf[wid][1][lane] = mq[1];
  mombuf[wid][2][lane] = mq2[0]; mombuf[wid][3][lane] = mq2[1];
  mombuf[wid][4][lane] = ms[0];  mombuf[wid][5][lane] = ms[1];
  mombuf[wid][6][lane] = ms2[0]; mombuf[wid][7][lane] = ms2[1];
  __syncthreads();

  float* w = part + (size_t)bid * PSTRIDE;
  if (tid < 64) {     // partial G (C/D layout col=lane&15, row=(lane>>4)*4+i — m89-verified)
    #pragma unroll
    for (int q = 0; q < 4; ++q) {
      f32x4 rsum = *reinterpret_cast<const f32x4*>(&accbuf[0][lane][q * 4]);
      #pragma unroll
      for (int ww = 1; ww < 5; ++ww)
        rsum += *reinterpret_cast<const f32x4*>(&accbuf[ww][lane][q * 4]);
      const int tr = q >> 1, tc = q & 1;
      #pragma unroll
      for (int i = 0; i < 4; ++i) {
        int u = tr * 16 + (lane >> 4) * 4 + i;
        int v = tc * 16 + (lane & 15);
        if (u < 25 && v < 25) w[u * 25 + v] = rsum[i];
      }
    }
  } else if (tid >= 64 && tid < 164) {   // partial moments: vt = {sQ, ssQ, sS, ssS}
    const int mt = tid - 64;
    const int vt = mt / 25, col = mt % 25;
    const int base = vt * 2;                       // 0,2,4,6
    const int t = (col < 16) ? 0 : 1, rr = col & 15;
    float s = 0.f;
    #pragma unroll
    for (int ww = 0; ww < 5; ++ww)
      #pragma unroll
      for (int gg = 0; gg < 4; ++gg)
        s += mombuf[ww][base + t][gg * 16 + rr];
    w[625 + vt * 25 + col] = s;
  }
}

// ---------- Kernel 2: combine halves + sim + Sinkhorn, one wave/sample ----------
__global__ __launch_bounds__(64) void emd_sink(
    const float* __restrict__ part, float* __restrict__ out)
{
  const int n = blockIdx.x, tid = threadIdx.x;
  const float* p0 = part + (size_t)(2 * n) * PSTRIDE;
  const float* p1 = part + (size_t)(2 * n + 1) * PSTRIDE;

  __shared__ float G[625];
  __shared__ float sQv[25], sSv[25], nqv[25], nsv[25], amv[25], bmv[25], scal[2];

  for (int p = tid; p < 625; p += 64) G[p] = p0[p] + p1[p];
  __syncthreads();

  if (tid < 25) {
    float s  = p0[625 + tid] + p1[625 + tid];
    float ss = p0[650 + tid] + p1[650 + tid];
    sQv[tid] = s;
    float var = ss - s * s * (1.f / C);
    nqv[tid] = fmaxf(sqrtf(fmaxf(var, 0.f)), 1e-8f);
    float rs = 0.f;
    #pragma unroll
    for (int j = 0; j < 25; ++j) rs += G[tid * 25 + j];
    amv[tid] = fmaxf(rs * (1.f / 25.f), 0.f) + 0.001f + 1e-5f;
  } else if (tid >= 32 && tid < 57) {
    const int v = tid - 32;
    float s  = p0[675 + v] + p1[675 + v];
    float ss = p0[700 + v] + p1[700 + v];
    sSv[v] = s;
    float var = ss - s * s * (1.f / C);
    nsv[v] = fmaxf(sqrtf(fmaxf(var, 0.f)), 1e-8f);
    float cs = 0.f;
    #pragma unroll
    for (int u = 0; u < 25; ++u) cs += G[u * 25 + v];
    bmv[v] = fmaxf(cs * (1.f / 25.f), 0.f) + 0.001f + 1e-5f;
  }
  __syncthreads();
  if (tid == 0) {
    float s0 = 0.f, s1 = 0.f;
    #pragma unroll
    for (int i = 0; i < 25; ++i) { s0 += amv[i]; s1 += bmv[i]; }
    scal[0] = 25.f / s0; scal[1] = 25.f / s1;
  }
  __syncthreads();
  for (int p = tid; p < 625; p += 64) {     // sim in place
    int u = p / 25, v = p % 25;
    float cov = G[p] - sQv[u] * sSv[v] * (1.f / C);
    G[p] = cov / (nqv[u] * nsv[v]);
  }
  __syncthreads();

  const int u = (tid < 25) ? tid : 24;
  float simr[25], Krow[25], Kcol[25];
  #pragma unroll
  for (int j = 0; j < 25; ++j) simr[j] = G[u * 25 + j];
  #pragma unroll
  for (int j = 0; j < 25; ++j) Kcol[j] = __expf(-20.f * (1.f - G[j * 25 + u]));
  #pragma unroll
  for (int j = 0; j < 25; ++j) Krow[j] = __expf(-20.f * (1.f - simr[j]));
  const float a_u = amv[u] * scal[0], b_u = bmv[u] * scal[1];

  float vv = 1.0f, uu = 0.0f, vold = 1.0f;
  #pragma unroll 1
  for (int it = 0; it < 100; ++it) {
    float s0 = 0, s1 = 0, s2 = 0, s3 = 0, s4 = 0;
    #pragma unroll
    for (int j = 0; j < 25; j += 5) {
      s0 = fmaf(Krow[j + 0], rl(vv, j + 0), s0);
      s1 = fmaf(Krow[j + 1], rl(vv, j + 1), s1);
      s2 = fmaf(Krow[j + 2], rl(vv, j + 2), s2);
      s3 = fmaf(Krow[j + 3], rl(vv, j + 3), s3);
      s4 = fmaf(Krow[j + 4], rl(vv, j + 4), s4);
    }
    uu = a_u * __builtin_amdgcn_rcpf(((((s0 + s1) + (s2 + s3)) + s4) + 1e-30f));

    s0 = s1 = s2 = s3 = s4 = 0;
    #pragma unroll
    for (int j = 0; j < 25; j += 5) {
      s0 = fmaf(Kcol[j + 0], rl(uu, j + 0), s0);
      s1 = fmaf(Kcol[j + 1], rl(uu, j + 1), s1);
      s2 = fmaf(Kcol[j + 2], rl(uu, j + 2), s2);
      s3 = fmaf(Kcol[j + 3], rl(uu, j + 3), s3);
      s4 = fmaf(Kcol[j + 4], rl(uu, j + 4), s4);
    }
    vv = b_u * __builtin_amdgcn_rcpf(((((s0 + s1) + (s2 + s3)) + s4) + 1e-30f));

    if ((it & 1) == 1) {
      bool conv = fabsf(vv - vold) <= 1e-4f * fabsf(vv);
      if (__all(conv)) break;
      vold = vv;
    }
  }
  {
    float s0 = 0, s1 = 0, s2 = 0, s3 = 0, s4 = 0;
    #pragma unroll
    for (int j = 0; j < 25; j += 5) {
      s0 = fmaf(Krow[j + 0], rl(vv, j + 0), s0);
      s1 = fmaf(Krow[j + 1], rl(vv, j + 1), s1);
      s2 = fmaf(Krow[j + 2], rl(vv, j + 2), s2);
      s3 = fmaf(Krow[j + 3], rl(vv, j + 3), s3);
      s4 = fmaf(Krow[j + 4], rl(vv, j + 4), s4);
    }
    uu = a_u * __builtin_amdgcn_rcpf(((((s0 + s1) + (s2 + s3)) + s4) + 1e-30f));
  }

  float pr = 0.f;
  if (tid < 25) {
    float t0 = 0.f;
    #pragma unroll
    for (int j = 0; j < 25; ++j)
      t0 = fmaf(simr[j] * Krow[j], rl(vv, j), t0);
    pr = uu * t0;
  }
  #pragma unroll
  for (int off = 32; off; off >>= 1) pr += __shfl_xor(pr, off);
  if (tid == 0) out[n] = pr * 0.5f;   // TEMPERATURE/hw = 12.5/25
}

extern "C" void kernel_launch(void* const* d_in, const int* in_sizes, int n_in,
                              void* d_out, int out_size, void* d_ws, size_t ws_size,
                              hipStream_t stream) {
  const float* support = (const float*)d_in[0];
  const float* query   = (const float*)d_in[1];
  float* out = (float*)d_out;
  float* partbuf = (float*)d_ws;
  const int N = in_sizes[0] / (C * HW);   // 600
  emd_gram<<<dim3(2 * N), dim3(320), 0, stream>>>(support, query, partbuf);
  emd_sink<<<dim3(N),     dim3(64),  0, stream>>>(partbuf, out);
}

// Round 14
// 24.891 us; speedup vs baseline: 1.2656x; 1.2656x over previous
//
#include <hip/hip_runtime.h>

typedef short bf16x8 __attribute__((ext_vector_type(8)));
typedef float f32x4  __attribute__((ext_vector_type(4)));

constexpr int C  = 640;
constexpr int HW = 25;

__device__ __forceinline__ float rl(float x, int lane) {
  return __uint_as_float(__builtin_amdgcn_readlane(__float_as_uint(x), lane));
}

// pack 2 fp32 -> (hi-bf16 pair, lo-bf16 pair), truncating split:
// hi = trunc_bf16(x); lo = trunc_bf16(x - hi)  (x-hi exact in fp32)
__device__ __forceinline__ void packpair(float x0, float x1, unsigned& h, unsigned& l) {
  unsigned u0 = __float_as_uint(x0), u1 = __float_as_uint(x1);
  h = __builtin_amdgcn_perm(u1, u0, 0x07060302u);      // [u1.hi16 : u0.hi16]
  float l0 = x0 - __uint_as_float(u0 & 0xFFFF0000u);
  float l1 = x1 - __uint_as_float(u1 & 0xFFFF0000u);
  l = __builtin_amdgcn_perm(__float_as_uint(l1), __float_as_uint(l0), 0x07060302u);
}

__global__ __launch_bounds__(256) void emd_fused(
    const float* __restrict__ support, const float* __restrict__ query,
    float* __restrict__ out)
{
  const int n = blockIdx.x, tid = threadIdx.x;
  const int wid = tid >> 6, lane = tid & 63;
  const int lg = lane >> 4, lr = lane & 15;   // channel sub-group, row-within-16

  __shared__ float accbuf[4][64][16];   // 16 KB
  __shared__ float mombuf[4][8][64];    // 8 KB
  __shared__ float G[625];
  __shared__ float sQv[25], sSv[25], nqv[25], nsv[25], amv[25], bmv[25], scal[2];

  const float* Qg = query   + (size_t)n * C * HW;
  const float* Sg = support + (size_t)n * C * HW;

  f32x4 acc[2][2];
  {
    f32x4 z = {0.f, 0.f, 0.f, 0.f};
    acc[0][0] = z; acc[0][1] = z; acc[1][0] = z; acc[1][1] = z;
  }
  float mq[2] = {0.f, 0.f}, mq2[2] = {0.f, 0.f};
  float ms[2] = {0.f, 0.f}, ms2[2] = {0.f, 0.f};

  // ---- Gram via MFMA, fragments loaded straight from global (no LDS, no barriers) ----
  #pragma unroll 1
  for (int s = 0; s < 5; ++s) {
    const int c0 = wid * 160 + s * 32 + lg * 8;   // 8 channels for this lane-group
    const float* qb = Qg + c0 * HW;
    const float* sb = Sg + c0 * HW;
    bf16x8 Ah[2], Al[2], Bh[2], Bl[2];
    #pragma unroll
    for (int t = 0; t < 2; ++t) {
      const int row = t * 16 + lr;
      const bool ok = row < 25;
      float xq[8], xs[8];
      #pragma unroll
      for (int j = 0; j < 8; ++j) {
        xq[j] = ok ? qb[j * HW + row] : 0.f;
        xs[j] = ok ? sb[j * HW + row] : 0.f;
      }
      #pragma unroll
      for (int j = 0; j < 8; ++j) {
        mq[t] += xq[j]; mq2[t] = fmaf(xq[j], xq[j], mq2[t]);
        ms[t] += xs[j]; ms2[t] = fmaf(xs[j], xs[j], ms2[t]);
      }
      union { unsigned u[4]; bf16x8 v; } ah, al, bh, bl;
      #pragma unroll
      for (int jj = 0; jj < 4; ++jj) {
        packpair(xq[2 * jj], xq[2 * jj + 1], ah.u[jj], al.u[jj]);
        packpair(xs[2 * jj], xs[2 * jj + 1], bh.u[jj], bl.u[jj]);
      }
      Ah[t] = ah.v; Al[t] = al.v; Bh[t] = bh.v; Bl[t] = bl.v;
    }
    #pragma unroll
    for (int tr = 0; tr < 2; ++tr)
      #pragma unroll
      for (int tc = 0; tc < 2; ++tc) {
        acc[tr][tc] = __builtin_amdgcn_mfma_f32_16x16x32_bf16(Ah[tr], Bh[tc], acc[tr][tc], 0, 0, 0);
        acc[tr][tc] = __builtin_amdgcn_mfma_f32_16x16x32_bf16(Ah[tr], Bl[tc], acc[tr][tc], 0, 0, 0);
        acc[tr][tc] = __builtin_amdgcn_mfma_f32_16x16x32_bf16(Al[tr], Bh[tc], acc[tr][tc], 0, 0, 0);
      }
  }

  // dump per-wave partials
  #pragma unroll
  for (int tr = 0; tr < 2; ++tr)
    #pragma unroll
    for (int tc = 0; tc < 2; ++tc)
      *reinterpret_cast<f32x4*>(&accbuf[wid][lane][(tr * 2 + tc) * 4]) = acc[tr][tc];
  mombuf[wid][0][lane] = mq[0];  mombuf[wid][1][lane] = mq[1];
  mombuf[wid][2][lane] = mq2[0]; mombuf[wid][3][lane] = mq2[1];
  mombuf[wid][4][lane] = ms[0];  mombuf[wid][5][lane] = ms[1];
  mombuf[wid][6][lane] = ms2[0]; mombuf[wid][7][lane] = ms2[1];
  __syncthreads();

  // cross-wave acc reduce -> G (C/D layout col=lane&15, row=(lane>>4)*4+i — m89-verified)
  if (tid < 64) {
    #pragma unroll
    for (int q = 0; q < 4; ++q) {
      f32x4 rsum = *reinterpret_cast<const f32x4*>(&accbuf[0][lane][q * 4]);
      #pragma unroll
      for (int w = 1; w < 4; ++w)
        rsum += *reinterpret_cast<const f32x4*>(&accbuf[w][lane][q * 4]);
      const int tr = q >> 1, tc = q & 1;
      #pragma unroll
      for (int i = 0; i < 4; ++i) {
        int u = tr * 16 + (lane >> 4) * 4 + i;
        int v = tc * 16 + (lane & 15);
        if (u < 25 && v < 25) G[u * 25 + v] = rsum[i];
      }
    }
  }
  __syncthreads();

  // moments + marginals
  if (tid < 25) {
    const int t = (tid < 16) ? 0 : 1, rr = tid - t * 16;
    float s = 0.f, ss = 0.f;
    #pragma unroll
    for (int w = 0; w < 4; ++w)
      #pragma unroll
      for (int gg = 0; gg < 4; ++gg) {
        s  += mombuf[w][0 + t][gg * 16 + rr];
        ss += mombuf[w][2 + t][gg * 16 + rr];
      }
    sQv[tid] = s;
    float var = ss - s * s * (1.f / C);
    nqv[tid] = fmaxf(sqrtf(fmaxf(var, 0.f)), 1e-8f);
    float rs = 0.f;
    #pragma unroll
    for (int j = 0; j < 25; ++j) rs += G[tid * 25 + j];
    amv[tid] = fmaxf(rs * (1.f / 25.f), 0.f) + 0.001f + 1e-5f;
  } else if (tid >= 32 && tid < 57) {
    const int v = tid - 32;
    const int t = (v < 16) ? 0 : 1, rr = v - t * 16;
    float s = 0.f, ss = 0.f;
    #pragma unroll
    for (int w = 0; w < 4; ++w)
      #pragma unroll
      for (int gg = 0; gg < 4; ++gg) {
        s  += mombuf[w][4 + t][gg * 16 + rr];
        ss += mombuf[w][6 + t][gg * 16 + rr];
      }
    sSv[v] = s;
    float var = ss - s * s * (1.f / C);
    nsv[v] = fmaxf(sqrtf(fmaxf(var, 0.f)), 1e-8f);
    float cs = 0.f;
    #pragma unroll
    for (int u = 0; u < 25; ++u) cs += G[u * 25 + v];
    bmv[v] = fmaxf(cs * (1.f / 25.f), 0.f) + 0.001f + 1e-5f;
  }
  __syncthreads();
  if (tid == 0)  { float s = 0.f; for (int i = 0; i < 25; ++i) s += amv[i]; scal[0] = 25.f / s; }
  if (tid == 64) { float s = 0.f; for (int i = 0; i < 25; ++i) s += bmv[i]; scal[1] = 25.f / s; }
  __syncthreads();
  for (int p = tid; p < 625; p += 256) {     // sim in place
    int u = p / 25, v = p % 25;
    float cov = G[p] - sQv[u] * sSv[v] * (1.f / C);
    G[p] = cov / (nqv[u] * nsv[v]);
  }
  __syncthreads();

  if (tid >= 64) return;                     // Sinkhorn on wave 0
  const int u = (tid < 25) ? tid : 24;
  float simr[25], Krow[25], Kcol[25];
  #pragma unroll
  for (int j = 0; j < 25; ++j) simr[j] = G[u * 25 + j];
  #pragma unroll
  for (int j = 0; j < 25; ++j) Kcol[j] = __expf(-20.f * (1.f - G[j * 25 + u]));
  #pragma unroll
  for (int j = 0; j < 25; ++j) Krow[j] = __expf(-20.f * (1.f - simr[j]));
  const float a_u = amv[u] * scal[0], b_u = bmv[u] * scal[1];

  float vv = 1.0f, uu = 0.0f, vold = 1.0f;
  #pragma unroll 1
  for (int it = 0; it < 100; ++it) {
    float s0 = 0, s1 = 0, s2 = 0, s3 = 0, s4 = 0;
    #pragma unroll
    for (int j = 0; j < 25; j += 5) {
      s0 = fmaf(Krow[j + 0], rl(vv, j + 0), s0);
      s1 = fmaf(Krow[j + 1], rl(vv, j + 1), s1);
      s2 = fmaf(Krow[j + 2], rl(vv, j + 2), s2);
      s3 = fmaf(Krow[j + 3], rl(vv, j + 3), s3);
      s4 = fmaf(Krow[j + 4], rl(vv, j + 4), s4);
    }
    uu = a_u * __builtin_amdgcn_rcpf(((((s0 + s1) + (s2 + s3)) + s4) + 1e-30f));

    s0 = s1 = s2 = s3 = s4 = 0;
    #pragma unroll
    for (int j = 0; j < 25; j += 5) {
      s0 = fmaf(Kcol[j + 0], rl(uu, j + 0), s0);
      s1 = fmaf(Kcol[j + 1], rl(uu, j + 1), s1);
      s2 = fmaf(Kcol[j + 2], rl(uu, j + 2), s2);
      s3 = fmaf(Kcol[j + 3], rl(uu, j + 3), s3);
      s4 = fmaf(Kcol[j + 4], rl(uu, j + 4), s4);
    }
    vv = b_u * __builtin_amdgcn_rcpf(((((s0 + s1) + (s2 + s3)) + s4) + 1e-30f));

    if ((it & 1) == 1) {
      bool conv = fabsf(vv - vold) <= 1e-4f * fabsf(vv);
      if (__all(conv)) break;
      vold = vv;
    }
  }
  {
    float s0 = 0, s1 = 0, s2 = 0, s3 = 0, s4 = 0;
    #pragma unroll
    for (int j = 0; j < 25; j += 5) {
      s0 = fmaf(Krow[j + 0], rl(vv, j + 0), s0);
      s1 = fmaf(Krow[j + 1], rl(vv, j + 1), s1);
      s2 = fmaf(Krow[j + 2], rl(vv, j + 2), s2);
      s3 = fmaf(Krow[j + 3], rl(vv, j + 3), s3);
      s4 = fmaf(Krow[j + 4], rl(vv, j + 4), s4);
    }
    uu = a_u * __builtin_amdgcn_rcpf(((((s0 + s1) + (s2 + s3)) + s4) + 1e-30f));
  }

  float pr = 0.f;
  if (tid < 25) {
    float t0 = 0.f;
    #pragma unroll
    for (int j = 0; j < 25; ++j)
      t0 = fmaf(simr[j] * Krow[j], rl(vv, j), t0);
    pr = uu * t0;
  }
  #pragma unroll
  for (int off = 32; off; off >>= 1) pr += __shfl_xor(pr, off);
  if (tid == 0) out[n] = pr * 0.5f;   // TEMPERATURE/hw = 12.5/25
}

extern "C" void kernel_launch(void* const* d_in, const int* in_sizes, int n_in,
                              void* d_out, int out_size, void* d_ws, size_t ws_size,
                              hipStream_t stream) {
  const float* support = (const float*)d_in[0];
  const float* query   = (const float*)d_in[1];
  float* out = (float*)d_out;
  const int N = in_sizes[0] / (C * HW);   // 600
  emd_fused<<<dim3(N), dim3(256), 0, stream>>>(support, query, out);
}